// Round 12
// baseline (188.730 us; speedup 1.0000x reference)
//
#include <hip/hip_runtime.h>

#define S_LEN 2048
#define BATCH 2
#define DM    1024
#define NH    16
#define NKV   4
#define HD    64
#define MROWS (BATCH * S_LEN)   // 4096
#define NQKV  1536              // 1024 q + 512 kv

typedef __attribute__((ext_vector_type(8))) short bf16x8;
typedef __attribute__((ext_vector_type(4))) short s16x4;
typedef __attribute__((ext_vector_type(4))) float f32x4;
typedef __attribute__((ext_vector_type(4))) int i32x4;

__device__ __forceinline__ unsigned short f2bf(float f) {
  unsigned int u = __float_as_uint(f);
  u += 0x7FFF + ((u >> 16) & 1);   // RNE
  return (unsigned short)(u >> 16);
}

__device__ __forceinline__ void gload_lds16(const unsigned short* g, unsigned short* l) {
  __builtin_amdgcn_global_load_lds((const __attribute__((address_space(1))) void*)g,
                                   (__attribute__((address_space(3))) void*)l, 16, 0, 0);
}
__device__ __forceinline__ void gload_lds4(const unsigned short* g, unsigned short* l) {
  __builtin_amdgcn_global_load_lds((const __attribute__((address_space(1))) void*)g,
                                   (__attribute__((address_space(3))) void*)l, 4, 0, 0);
}

// ------- prep: x->bf16 (blocks 0..4095) + all W transposes (blocks 4096..4735) -------
__global__ __launch_bounds__(256) void prep_kernel(const float* __restrict__ x,
                                                   unsigned short* __restrict__ xb,
                                                   const float* __restrict__ Wq,
                                                   const float* __restrict__ Wkv,
                                                   const float* __restrict__ Wo,
                                                   unsigned short* __restrict__ wt1,
                                                   unsigned short* __restrict__ wot) {
  __shared__ float tile[64][65];
  int bid = blockIdx.x;
  int t = threadIdx.x;
  if (bid < 4096) {
    int i = (bid * 256 + t) * 4;
    float4 v = *reinterpret_cast<const float4*>(x + i);
    xb[i + 0] = f2bf(v.x);
    xb[i + 1] = f2bf(v.y);
    xb[i + 2] = f2bf(v.z);
    xb[i + 3] = f2bf(v.w);
    return;
  }
  bid -= 4096;
  const float* in;
  unsigned short* out;
  int C, bx, by;
  if (bid < 256) { in = Wq; out = wt1; C = 1024; bx = bid & 15; by = bid >> 4; }
  else if (bid < 384) { int k = bid - 256; in = Wkv; out = wt1 + 1024 * 1024; C = 512; bx = k & 7; by = k >> 3; }
  else { int k = bid - 384; in = Wo; out = wot; C = 1024; bx = k & 15; by = k >> 4; }
  const int R = 1024;
  int r0 = by * 64, c0 = bx * 64;
  int rl = t >> 2, cs = (t & 3) * 16;
#pragma unroll
  for (int k = 0; k < 4; ++k) {
    float4 v = *reinterpret_cast<const float4*>(in + (size_t)(r0 + rl) * C + c0 + cs + 4 * k);
    tile[rl][cs + 4 * k + 0] = v.x;
    tile[rl][cs + 4 * k + 1] = v.y;
    tile[rl][cs + 4 * k + 2] = v.z;
    tile[rl][cs + 4 * k + 3] = v.w;
  }
  __syncthreads();
  int cl = t >> 2, rs = (t & 3) * 16;
  bf16x8 v0, v1;
#pragma unroll
  for (int i = 0; i < 8; ++i) v0[i] = (short)f2bf(tile[rs + i][cl]);
#pragma unroll
  for (int i = 0; i < 8; ++i) v1[i] = (short)f2bf(tile[rs + 8 + i][cl]);
  unsigned short* dst = out + (size_t)(c0 + cl) * R + r0 + rs;
  *reinterpret_cast<bf16x8*>(dst) = v0;
  *reinterpret_cast<bf16x8*>(dst + 8) = v1;
}

// ------- gemm1 FUSED: qkv = xb @ wt1^T, 128x64 tile, epilogue RMSNorm+RoPE -------
// r5-proven config: BK=64, single-buffered (dbuf/BK=128 both measured-worse).
__global__ __launch_bounds__(256) void gemm1_fused(const unsigned short* __restrict__ A,
                                                   const unsigned short* __restrict__ BT,
                                                   const float* __restrict__ q_scale,
                                                   const float* __restrict__ k_scale,
                                                   unsigned short* __restrict__ qb,
                                                   unsigned short* __restrict__ kbuf,
                                                   unsigned short* __restrict__ vt,
                                                   int K) {
  __shared__ __align__(16) unsigned short As[128 * 64];
  __shared__ __align__(16) unsigned short Bs[64 * 64];
  int bx = blockIdx.x;
  int row0 = blockIdx.y * 128, col0 = bx * 64;
  int t = threadIdx.x;
  int w = t >> 6, lane = t & 63, quad = lane >> 4, l16 = lane & 15;
  int srow = lane >> 3;
  int scol = (lane & 7) * 8;

  f32x4 acc[2][4];
#pragma unroll
  for (int i = 0; i < 2; ++i)
#pragma unroll
    for (int j = 0; j < 4; ++j) acc[i][j] = (f32x4){0.f, 0.f, 0.f, 0.f};

  for (int k0 = 0; k0 < K; k0 += 64) {
#pragma unroll
    for (int j = 0; j < 4; ++j)
      gload_lds16(A + (size_t)(row0 + w * 32 + j * 8 + srow) * K + k0 + scol,
                  &As[(w * 32 + j * 8) * 64]);
#pragma unroll
    for (int j = 0; j < 2; ++j)
      gload_lds16(BT + (size_t)(col0 + w * 16 + j * 8 + srow) * K + k0 + scol,
                  &Bs[(w * 16 + j * 8) * 64]);
    __syncthreads();
#pragma unroll
    for (int ks = 0; ks < 2; ++ks) {
      bf16x8 af[2], bfr[4];
#pragma unroll
      for (int i = 0; i < 2; ++i)
        af[i] = *reinterpret_cast<const bf16x8*>(&As[(w * 32 + i * 16 + l16) * 64 + ks * 32 + quad * 8]);
#pragma unroll
      for (int j = 0; j < 4; ++j)
        bfr[j] = *reinterpret_cast<const bf16x8*>(&Bs[(j * 16 + l16) * 64 + ks * 32 + quad * 8]);
#pragma unroll
      for (int i = 0; i < 2; ++i)
#pragma unroll
        for (int j = 0; j < 4; ++j)
          acc[i][j] = __builtin_amdgcn_mfma_f32_16x16x32_bf16(af[i], bfr[j], acc[i][j], 0, 0, 0);
    }
    __syncthreads();
  }

  if (bx < 20) {
    const float* scale = (bx < 16) ? q_scale : k_scale;
    float post = (bx < 16) ? 1.0f : 0.125f * 1.44269504088896f;
    float sc0 = scale[l16], sc1 = scale[16 + l16], sc2 = scale[32 + l16], sc3 = scale[48 + l16];
    float invf0 = exp2f((float)l16 * (-13.2877123795495f / 32.0f));
    float invf1 = exp2f((float)(l16 + 16) * (-13.2877123795495f / 32.0f));
#pragma unroll
    for (int i = 0; i < 2; ++i)
#pragma unroll
      for (int rg = 0; rg < 4; ++rg) {
        int row = row0 + w * 32 + i * 16 + quad * 4 + rg;
        int b = row >> 11, s = row & 2047;
        float v0 = acc[i][0][rg], v1 = acc[i][1][rg], v2 = acc[i][2][rg], v3 = acc[i][3][rg];
        float ss = v0 * v0 + v1 * v1 + v2 * v2 + v3 * v3;
        ss += __shfl_xor(ss, 1, 64);
        ss += __shfl_xor(ss, 2, 64);
        ss += __shfl_xor(ss, 4, 64);
        ss += __shfl_xor(ss, 8, 64);
        float inv_rms = 1.0f / sqrtf(ss * (1.0f / 64.0f) + 1e-5f);
        float n0 = v0 * inv_rms * sc0, n1 = v1 * inv_rms * sc1;
        float n2 = v2 * inv_rms * sc2, n3 = v3 * inv_rms * sc3;
        float f0 = (float)s * invf0, f1 = (float)s * invf1;
        float c0 = __cosf(f0), s0 = __sinf(f0), c1 = __cosf(f1), s1 = __sinf(f1);
        float o0 = (n0 * c0 - n2 * s0) * post;
        float o1 = (n1 * c1 - n3 * s1) * post;
        float o2 = (n0 * s0 + n2 * c0) * post;
        float o3 = (n1 * s1 + n3 * c1) * post;
        unsigned short* dst = (bx < 16)
            ? qb + ((size_t)(b * NH + bx) * S_LEN + s) * HD
            : kbuf + ((size_t)(b * NKV + (bx - 16)) * S_LEN + s) * HD;
        dst[l16] = f2bf(o0);
        dst[16 + l16] = f2bf(o1);
        dst[32 + l16] = f2bf(o2);
        dst[48 + l16] = f2bf(o3);
      }
  } else {
    int kvh = bx - 20;
    int b = row0 >> 11;
    unsigned short* vbase = vt + (size_t)(b * NKV + kvh) * HD * S_LEN;
#pragma unroll
    for (int i = 0; i < 2; ++i) {
      int s0 = (row0 & 2047) + w * 32 + i * 16 + quad * 4;
#pragma unroll
      for (int j = 0; j < 4; ++j) {
        int d = j * 16 + l16;
        s16x4 pv;
#pragma unroll
        for (int rg = 0; rg < 4; ++rg) pv[rg] = (short)f2bf(acc[i][j][rg]);
        *reinterpret_cast<s16x4*>(vbase + (size_t)d * S_LEN + s0) = pv;
      }
    }
  }
}

// ------- causal flash attention: split-S(2), GQA-shared, LDS-staged (r5 structure) -------
// + T5 setprio (null-within-noise, kept). P-transpose eliminated via permuted K-row
// loads (r3). LDS 34.8 KB/block -> 4 blocks/CU; launch_bounds(256,4).
#define CH 136                 // shorts per chunk: 256B data + 16B pad
#define TILE_SH (32 * CH)
__global__ __launch_bounds__(256, 4) void attn_kernel(const unsigned short* __restrict__ qb,
                                                      const unsigned short* __restrict__ kbuf,
                                                      const unsigned short* __restrict__ vt,
                                                      unsigned short* __restrict__ Opart,
                                                      float* __restrict__ lpart) {
  __shared__ __align__(16) unsigned short Ks[2][TILE_SH];
  __shared__ __align__(16) unsigned short Vs[2][TILE_SH];
  const size_t OZ = (size_t)BATCH * NH * S_LEN * HD;
  const size_t LZ = (size_t)BATCH * NH * S_LEN;
  int t32 = 63 - (int)(blockIdx.x >> 4);   // heavy tiles dispatched first
  int sub = blockIdx.x & 15;
  int z = sub & 1;
  int bkv = sub >> 1;
  int b = bkv >> 2, kvh = bkv & 3;
  int w = threadIdx.x >> 6;                // head within kv group
  int h = kvh * 4 + w;
  int lane = threadIdx.x & 63;
  int quad = lane >> 4, l16 = lane & 15;
  int qa = t32 * 32 + l16;                 // q-group a; group b = qa + 16
  const unsigned short* Q = qb + (size_t)(b * NH + h) * S_LEN * HD;
  const unsigned short* Kh = kbuf + (size_t)(b * NKV + kvh) * S_LEN * HD;
  const unsigned short* Vh = vt + (size_t)(b * NKV + kvh) * HD * S_LEN;

  bf16x8 bqa0 = *reinterpret_cast<const bf16x8*>(Q + (size_t)qa * HD + quad * 8);
  bf16x8 bqa1 = *reinterpret_cast<const bf16x8*>(Q + (size_t)qa * HD + 32 + quad * 8);
  bf16x8 bqb0 = *reinterpret_cast<const bf16x8*>(Q + (size_t)(qa + 16) * HD + quad * 8);
  bf16x8 bqb1 = *reinterpret_cast<const bf16x8*>(Q + (size_t)(qa + 16) * HD + 32 + quad * 8);

  bf16x8 ones;
#pragma unroll
  for (int i = 0; i < 8; ++i) ones[i] = (short)0x3F80;   // bf16 1.0

  f32x4 ot[2][4];
#pragma unroll
  for (int gq = 0; gq < 2; ++gq)
#pragma unroll
    for (int i = 0; i < 4; ++i) ot[gq][i] = (f32x4){0.f, 0.f, 0.f, 0.f};
  f32x4 ol[2] = {(f32x4){0.f, 0.f, 0.f, 0.f}, (f32x4){0.f, 0.f, 0.f, 0.f}};

  int n = (t32 >> 1) + 1;                  // key tiles for this q-tile

  auto stage = [&](int kbase, int dbuf) {
    const unsigned short* kg = Kh + (size_t)(kbase + w * 16) * HD + lane * 2;
    const unsigned short* vg = Vh + (size_t)(w * 16 + (lane >> 5)) * S_LEN + kbase + (lane & 31) * 2;
    unsigned short* kl = &Ks[dbuf][(w * 8) * CH];
    unsigned short* vl = &Vs[dbuf][(w * 8) * CH];
#pragma unroll
    for (int c = 0; c < 8; ++c) {
      gload_lds4(kg + (size_t)(2 * c) * HD, kl + c * CH);
      gload_lds4(vg + (size_t)(2 * c) * S_LEN, vl + c * CH);
    }
  };

  if (z < n) {
    stage(z << 6, 0);
    __syncthreads();

    for (int kb = z; kb < n; kb += 2) {
      int dbuf = (kb >> 1) & 1;
      bool diag = (kb == n - 1);
      if (kb + 2 < n) stage((kb + 2) << 6, dbuf ^ 1);
      int kbase = kb << 6;
      const unsigned short* Kd = Ks[dbuf];
      const unsigned short* Vd = Vs[dbuf];

      f32x4 sa[4], sb[4];
      __builtin_amdgcn_s_setprio(1);
#pragma unroll
      for (int km = 0; km < 4; ++km) {
        // permuted key row for MFMA km at A-row l16
        int kk = 32 * (km >> 1) + 4 * (km & 1) + 8 * (l16 >> 2) + (l16 & 3);
        int base = (kk >> 1) * CH + (kk & 1) * 64;
        bf16x8 k0 = *reinterpret_cast<const bf16x8*>(&Kd[base + quad * 8]);
        bf16x8 k1 = *reinterpret_cast<const bf16x8*>(&Kd[base + 32 + quad * 8]);
        f32x4 s = {0.f, 0.f, 0.f, 0.f};
        s = __builtin_amdgcn_mfma_f32_16x16x32_bf16(k0, bqa0, s, 0, 0, 0);
        s = __builtin_amdgcn_mfma_f32_16x16x32_bf16(k1, bqa1, s, 0, 0, 0);
        sa[km] = s;
        f32x4 s2 = {0.f, 0.f, 0.f, 0.f};
        s2 = __builtin_amdgcn_mfma_f32_16x16x32_bf16(k0, bqb0, s2, 0, 0, 0);
        s2 = __builtin_amdgcn_mfma_f32_16x16x32_bf16(k1, bqb1, s2, 0, 0, 0);
        sb[km] = s2;
      }
      __builtin_amdgcn_s_setprio(0);
      if (diag) {
#pragma unroll
        for (int km = 0; km < 4; ++km)
#pragma unroll
          for (int rg = 0; rg < 4; ++rg) {
            int key = kbase + 32 * (km >> 1) + 8 * quad + 4 * (km & 1) + rg;
            if (key > qa) sa[km][rg] = -1e30f;
            if (key > qa + 16) sb[km][rg] = -1e30f;
          }
      }
      unsigned int pk[4][2], qk[4][2];
#pragma unroll
      for (int km = 0; km < 4; ++km) {
        float a0 = exp2f(sa[km][0]), a1 = exp2f(sa[km][1]);
        float a2 = exp2f(sa[km][2]), a3 = exp2f(sa[km][3]);
        pk[km][0] = __builtin_amdgcn_perm(__float_as_uint(a1), __float_as_uint(a0), 0x07060302);
        pk[km][1] = __builtin_amdgcn_perm(__float_as_uint(a3), __float_as_uint(a2), 0x07060302);
        float b0 = exp2f(sb[km][0]), b1 = exp2f(sb[km][1]);
        float b2 = exp2f(sb[km][2]), b3 = exp2f(sb[km][3]);
        qk[km][0] = __builtin_amdgcn_perm(__float_as_uint(b1), __float_as_uint(b0), 0x07060302);
        qk[km][1] = __builtin_amdgcn_perm(__float_as_uint(b3), __float_as_uint(b2), 0x07060302);
      }
      i32x4 wa0 = {(int)pk[0][0], (int)pk[0][1], (int)pk[1][0], (int)pk[1][1]};
      i32x4 wa1 = {(int)pk[2][0], (int)pk[2][1], (int)pk[3][0], (int)pk[3][1]};
      i32x4 wb0 = {(int)qk[0][0], (int)qk[0][1], (int)qk[1][0], (int)qk[1][1]};
      i32x4 wb1 = {(int)qk[2][0], (int)qk[2][1], (int)qk[3][0], (int)qk[3][1]};
      bf16x8 pa0 = *reinterpret_cast<bf16x8*>(&wa0);
      bf16x8 pa1 = *reinterpret_cast<bf16x8*>(&wa1);
      bf16x8 pb0 = *reinterpret_cast<bf16x8*>(&wb0);
      bf16x8 pb1 = *reinterpret_cast<bf16x8*>(&wb1);
      __builtin_amdgcn_s_setprio(1);
      ol[0] = __builtin_amdgcn_mfma_f32_16x16x32_bf16(ones, pa0, ol[0], 0, 0, 0);
      ol[0] = __builtin_amdgcn_mfma_f32_16x16x32_bf16(ones, pa1, ol[0], 0, 0, 0);
      ol[1] = __builtin_amdgcn_mfma_f32_16x16x32_bf16(ones, pb0, ol[1], 0, 0, 0);
      ol[1] = __builtin_amdgcn_mfma_f32_16x16x32_bf16(ones, pb1, ol[1], 0, 0, 0);
#pragma unroll
      for (int dm = 0; dm < 4; ++dm) {
        int ch = dm * 8 + (l16 >> 1);
        int base = ch * CH + (l16 & 1) * 64;
        bf16x8 v0 = *reinterpret_cast<const bf16x8*>(&Vd[base + quad * 8]);
        bf16x8 v1 = *reinterpret_cast<const bf16x8*>(&Vd[base + 32 + quad * 8]);
        ot[0][dm] = __builtin_amdgcn_mfma_f32_16x16x32_bf16(v0, pa0, ot[0][dm], 0, 0, 0);
        ot[0][dm] = __builtin_amdgcn_mfma_f32_16x16x32_bf16(v1, pa1, ot[0][dm], 0, 0, 0);
        ot[1][dm] = __builtin_amdgcn_mfma_f32_16x16x32_bf16(v0, pb0, ot[1][dm], 0, 0, 0);
        ot[1][dm] = __builtin_amdgcn_mfma_f32_16x16x32_bf16(v1, pb1, ot[1][dm], 0, 0, 0);
      }
      __builtin_amdgcn_s_setprio(0);
      __syncthreads();   // drains prefetch (issued a full phase ago) + buffer swap
    }
  }

  // write unnormalized bf16 O partial + fp32 l partial for this z
  unsigned short* Oz = Opart + (size_t)z * OZ;
  float* lz = lpart + (size_t)z * LZ;
#pragma unroll
  for (int gq = 0; gq < 2; ++gq) {
    size_t base = ((size_t)(b * NH + h) * S_LEN + qa + gq * 16) * HD;
#pragma unroll
    for (int dm = 0; dm < 4; ++dm) {
      s16x4 pv;
#pragma unroll
      for (int rg = 0; rg < 4; ++rg) pv[rg] = (short)f2bf(ot[gq][dm][rg]);
      *reinterpret_cast<s16x4*>(Oz + base + dm * 16 + quad * 4) = pv;
    }
  }
  if (quad == 0) {
    size_t lb = (size_t)(b * NH + h) * S_LEN + t32 * 32 + l16;
    lz[lb] = ol[0][0];
    lz[lb + 16] = ol[1][0];
  }
}

// ------- gemm2 FUSED: out = ((O0+O1)/l) @ wot^T -------
// Combine folded into A-staging: K-step k0 covers exactly head h=k0>>6, so the
// A-tile rows map to contiguous Opart rows (b*NH+h)*S+q. Reg-staged combine
// (2x bf16x8 load + l-sum + scale) -> ds_write into XOR-swizzled As (colunit ^=
// row&7; legal since A no longer uses global_load_lds — rule #21 both-sides).
// Deletes the combine kernel, its launch gap, and the 8.4MB ctx round-trip.
__global__ __launch_bounds__(256) void gemm2_fused(const unsigned short* __restrict__ Opart,
                                                   const float* __restrict__ lpart,
                                                   const unsigned short* __restrict__ BT,
                                                   float* __restrict__ C) {
  const size_t OZ = (size_t)BATCH * NH * S_LEN * HD;
  const size_t LZ = (size_t)BATCH * NH * S_LEN;
  const int N = DM, K = DM;
  __shared__ __align__(16) unsigned short As[128 * 64];
  __shared__ __align__(16) unsigned short Bs[64 * 64];
  int row0 = blockIdx.y * 128, col0 = blockIdx.x * 64;
  int t = threadIdx.x;
  int w = t >> 6, lane = t & 63, quad = lane >> 4, l16 = lane & 15;
  int srow = lane >> 3;          // 0..7
  int scol = (lane & 7) * 8;     // 0..56

  f32x4 acc[2][4];
#pragma unroll
  for (int i = 0; i < 2; ++i)
#pragma unroll
    for (int j = 0; j < 4; ++j) acc[i][j] = (f32x4){0.f, 0.f, 0.f, 0.f};

  for (int k0 = 0; k0 < K; k0 += 64) {
    int h = k0 >> 6;
    // B: async global->LDS (linear, unchanged)
#pragma unroll
    for (int j = 0; j < 2; ++j)
      gload_lds16(BT + (size_t)(col0 + w * 16 + j * 8 + srow) * K + k0 + scol,
                  &Bs[(w * 16 + j * 8) * 64]);
    // A: reg-staged combine (O0+O1)*inv -> swizzled LDS
#pragma unroll
    for (int j = 0; j < 4; ++j) {
      int r = row0 + w * 32 + j * 8 + srow;
      int b = r >> 11, q = r & 2047;
      size_t orow = (size_t)(b * NH + h) * S_LEN + q;
      size_t off = orow * HD + scol;
      bf16x8 a0 = *reinterpret_cast<const bf16x8*>(Opart + off);
      bf16x8 a1 = *reinterpret_cast<const bf16x8*>(Opart + OZ + off);
      float inv = 1.0f / (lpart[orow] + lpart[LZ + orow]);
      bf16x8 o;
#pragma unroll
      for (int k = 0; k < 8; ++k) {
        float fa = __uint_as_float(((unsigned int)(unsigned short)a0[k]) << 16);
        float fc = __uint_as_float(((unsigned int)(unsigned short)a1[k]) << 16);
        o[k] = (short)f2bf((fa + fc) * inv);
      }
      int colu = (scol >> 3) ^ srow;   // XOR swizzle within row (8x 16B units)
      *reinterpret_cast<bf16x8*>(&As[(w * 32 + j * 8 + srow) * 64 + (colu << 3)]) = o;
    }
    __syncthreads();
#pragma unroll
    for (int ks = 0; ks < 2; ++ks) {
      bf16x8 af[2], bfr[4];
#pragma unroll
      for (int i = 0; i < 2; ++i) {
        int arow = w * 32 + i * 16 + l16;
        int colu = (ks * 4 + quad) ^ (l16 & 7);   // matching read-side swizzle
        af[i] = *reinterpret_cast<const bf16x8*>(&As[arow * 64 + (colu << 3)]);
      }
#pragma unroll
      for (int j = 0; j < 4; ++j)
        bfr[j] = *reinterpret_cast<const bf16x8*>(&Bs[(j * 16 + l16) * 64 + ks * 32 + quad * 8]);
#pragma unroll
      for (int i = 0; i < 2; ++i)
#pragma unroll
        for (int j = 0; j < 4; ++j)
          acc[i][j] = __builtin_amdgcn_mfma_f32_16x16x32_bf16(af[i], bfr[j], acc[i][j], 0, 0, 0);
    }
    __syncthreads();
  }
#pragma unroll
  for (int i = 0; i < 2; ++i)
#pragma unroll
    for (int j = 0; j < 4; ++j) {
      int row = row0 + w * 32 + i * 16 + quad * 4;
      float* Cptr = C + (size_t)row * N + col0 + j * 16 + l16;
#pragma unroll
      for (int rg = 0; rg < 4; ++rg) Cptr[(size_t)rg * N] = acc[i][j][rg];
    }
}

// ---------------- launch ----------------
extern "C" void kernel_launch(void* const* d_in, const int* in_sizes, int n_in,
                              void* d_out, int out_size, void* d_ws, size_t ws_size,
                              hipStream_t stream) {
  const float* x = (const float*)d_in[0];
  const float* Wq = (const float*)d_in[1];
  const float* Wkv = (const float*)d_in[2];
  const float* Wo = (const float*)d_in[3];
  const float* q_scale = (const float*)d_in[4];
  const float* k_scale = (const float*)d_in[5];
  float* out = (float*)d_out;

  char* ws = (char*)d_ws;
  size_t off = 0;
  auto alloc = [&](size_t bytes) {
    void* p = ws + off;
    off += (bytes + 255) & ~(size_t)255;
    return p;
  };
  unsigned short* xb = (unsigned short*)alloc((size_t)MROWS * DM * 2);
  unsigned short* wt1 = (unsigned short*)alloc((size_t)NQKV * DM * 2);   // [Wq^T ; Wkv^T]
  unsigned short* wot = (unsigned short*)alloc((size_t)DM * DM * 2);
  unsigned short* qb = (unsigned short*)alloc((size_t)BATCH * NH * S_LEN * HD * 2);
  unsigned short* kbuf = (unsigned short*)alloc((size_t)BATCH * NKV * S_LEN * HD * 2);
  unsigned short* vt = (unsigned short*)alloc((size_t)BATCH * NKV * HD * S_LEN * 2);
  unsigned short* Opart = (unsigned short*)alloc(2 * (size_t)BATCH * NH * S_LEN * HD * 2);
  float* lpart = (float*)alloc(2 * (size_t)BATCH * NH * S_LEN * 4);

  prep_kernel<<<4736, 256, 0, stream>>>(x, xb, Wq, Wkv, Wo, wt1, wot);

  gemm1_fused<<<dim3(NQKV / 64, MROWS / 128), 256, 0, stream>>>(xb, wt1, q_scale, k_scale,
                                                                qb, kbuf, vt, DM);

  attn_kernel<<<1024, 256, 0, stream>>>(qb, kbuf, vt, Opart, lpart);

  gemm2_fused<<<dim3(DM / 64, MROWS / 128), 256, 0, stream>>>(Opart, lpart, wot, out);
}

// Round 13
// 170.901 us; speedup vs baseline: 1.1043x; 1.1043x over previous
//
#include <hip/hip_runtime.h>

#define S_LEN 2048
#define BATCH 2
#define DM    1024
#define NH    16
#define NKV   4
#define HD    64
#define MROWS (BATCH * S_LEN)   // 4096
#define NQKV  1536              // 1024 q + 512 kv

typedef __attribute__((ext_vector_type(8))) short bf16x8;
typedef __attribute__((ext_vector_type(4))) short s16x4;
typedef __attribute__((ext_vector_type(4))) float f32x4;
typedef __attribute__((ext_vector_type(4))) int i32x4;

__device__ __forceinline__ unsigned short f2bf(float f) {
  unsigned int u = __float_as_uint(f);
  u += 0x7FFF + ((u >> 16) & 1);   // RNE
  return (unsigned short)(u >> 16);
}

__device__ __forceinline__ void gload_lds16(const unsigned short* g, unsigned short* l) {
  __builtin_amdgcn_global_load_lds((const __attribute__((address_space(1))) void*)g,
                                   (__attribute__((address_space(3))) void*)l, 16, 0, 0);
}
__device__ __forceinline__ void gload_lds4(const unsigned short* g, unsigned short* l) {
  __builtin_amdgcn_global_load_lds((const __attribute__((address_space(1))) void*)g,
                                   (__attribute__((address_space(3))) void*)l, 4, 0, 0);
}

// ------- prep: x->bf16 (blocks 0..4095) + all W transposes (blocks 4096..4735) -------
__global__ __launch_bounds__(256) void prep_kernel(const float* __restrict__ x,
                                                   unsigned short* __restrict__ xb,
                                                   const float* __restrict__ Wq,
                                                   const float* __restrict__ Wkv,
                                                   const float* __restrict__ Wo,
                                                   unsigned short* __restrict__ wt1,
                                                   unsigned short* __restrict__ wot) {
  __shared__ float tile[64][65];
  int bid = blockIdx.x;
  int t = threadIdx.x;
  if (bid < 4096) {
    int i = (bid * 256 + t) * 4;
    float4 v = *reinterpret_cast<const float4*>(x + i);
    xb[i + 0] = f2bf(v.x);
    xb[i + 1] = f2bf(v.y);
    xb[i + 2] = f2bf(v.z);
    xb[i + 3] = f2bf(v.w);
    return;
  }
  bid -= 4096;
  const float* in;
  unsigned short* out;
  int C, bx, by;
  if (bid < 256) { in = Wq; out = wt1; C = 1024; bx = bid & 15; by = bid >> 4; }
  else if (bid < 384) { int k = bid - 256; in = Wkv; out = wt1 + 1024 * 1024; C = 512; bx = k & 7; by = k >> 3; }
  else { int k = bid - 384; in = Wo; out = wot; C = 1024; bx = k & 15; by = k >> 4; }
  const int R = 1024;
  int r0 = by * 64, c0 = bx * 64;
  int rl = t >> 2, cs = (t & 3) * 16;
#pragma unroll
  for (int k = 0; k < 4; ++k) {
    float4 v = *reinterpret_cast<const float4*>(in + (size_t)(r0 + rl) * C + c0 + cs + 4 * k);
    tile[rl][cs + 4 * k + 0] = v.x;
    tile[rl][cs + 4 * k + 1] = v.y;
    tile[rl][cs + 4 * k + 2] = v.z;
    tile[rl][cs + 4 * k + 3] = v.w;
  }
  __syncthreads();
  int cl = t >> 2, rs = (t & 3) * 16;
  bf16x8 v0, v1;
#pragma unroll
  for (int i = 0; i < 8; ++i) v0[i] = (short)f2bf(tile[rs + i][cl]);
#pragma unroll
  for (int i = 0; i < 8; ++i) v1[i] = (short)f2bf(tile[rs + 8 + i][cl]);
  unsigned short* dst = out + (size_t)(c0 + cl) * R + r0 + rs;
  *reinterpret_cast<bf16x8*>(dst) = v0;
  *reinterpret_cast<bf16x8*>(dst + 8) = v1;
}

// ------- gemm1 FUSED: qkv = xb @ wt1^T, 128x64 tile, epilogue RMSNorm+RoPE -------
// r5-proven config: BK=64, single-buffered (dbuf/BK=128 both measured-worse).
__global__ __launch_bounds__(256) void gemm1_fused(const unsigned short* __restrict__ A,
                                                   const unsigned short* __restrict__ BT,
                                                   const float* __restrict__ q_scale,
                                                   const float* __restrict__ k_scale,
                                                   unsigned short* __restrict__ qb,
                                                   unsigned short* __restrict__ kbuf,
                                                   unsigned short* __restrict__ vt,
                                                   int K) {
  __shared__ __align__(16) unsigned short As[128 * 64];
  __shared__ __align__(16) unsigned short Bs[64 * 64];
  int bx = blockIdx.x;
  int row0 = blockIdx.y * 128, col0 = bx * 64;
  int t = threadIdx.x;
  int w = t >> 6, lane = t & 63, quad = lane >> 4, l16 = lane & 15;
  int srow = lane >> 3;
  int scol = (lane & 7) * 8;

  f32x4 acc[2][4];
#pragma unroll
  for (int i = 0; i < 2; ++i)
#pragma unroll
    for (int j = 0; j < 4; ++j) acc[i][j] = (f32x4){0.f, 0.f, 0.f, 0.f};

  for (int k0 = 0; k0 < K; k0 += 64) {
#pragma unroll
    for (int j = 0; j < 4; ++j)
      gload_lds16(A + (size_t)(row0 + w * 32 + j * 8 + srow) * K + k0 + scol,
                  &As[(w * 32 + j * 8) * 64]);
#pragma unroll
    for (int j = 0; j < 2; ++j)
      gload_lds16(BT + (size_t)(col0 + w * 16 + j * 8 + srow) * K + k0 + scol,
                  &Bs[(w * 16 + j * 8) * 64]);
    __syncthreads();
#pragma unroll
    for (int ks = 0; ks < 2; ++ks) {
      bf16x8 af[2], bfr[4];
#pragma unroll
      for (int i = 0; i < 2; ++i)
        af[i] = *reinterpret_cast<const bf16x8*>(&As[(w * 32 + i * 16 + l16) * 64 + ks * 32 + quad * 8]);
#pragma unroll
      for (int j = 0; j < 4; ++j)
        bfr[j] = *reinterpret_cast<const bf16x8*>(&Bs[(j * 16 + l16) * 64 + ks * 32 + quad * 8]);
#pragma unroll
      for (int i = 0; i < 2; ++i)
#pragma unroll
        for (int j = 0; j < 4; ++j)
          acc[i][j] = __builtin_amdgcn_mfma_f32_16x16x32_bf16(af[i], bfr[j], acc[i][j], 0, 0, 0);
    }
    __syncthreads();
  }

  if (bx < 20) {
    const float* scale = (bx < 16) ? q_scale : k_scale;
    float post = (bx < 16) ? 1.0f : 0.125f * 1.44269504088896f;
    float sc0 = scale[l16], sc1 = scale[16 + l16], sc2 = scale[32 + l16], sc3 = scale[48 + l16];
    float invf0 = exp2f((float)l16 * (-13.2877123795495f / 32.0f));
    float invf1 = exp2f((float)(l16 + 16) * (-13.2877123795495f / 32.0f));
#pragma unroll
    for (int i = 0; i < 2; ++i)
#pragma unroll
      for (int rg = 0; rg < 4; ++rg) {
        int row = row0 + w * 32 + i * 16 + quad * 4 + rg;
        int b = row >> 11, s = row & 2047;
        float v0 = acc[i][0][rg], v1 = acc[i][1][rg], v2 = acc[i][2][rg], v3 = acc[i][3][rg];
        float ss = v0 * v0 + v1 * v1 + v2 * v2 + v3 * v3;
        ss += __shfl_xor(ss, 1, 64);
        ss += __shfl_xor(ss, 2, 64);
        ss += __shfl_xor(ss, 4, 64);
        ss += __shfl_xor(ss, 8, 64);
        float inv_rms = 1.0f / sqrtf(ss * (1.0f / 64.0f) + 1e-5f);
        float n0 = v0 * inv_rms * sc0, n1 = v1 * inv_rms * sc1;
        float n2 = v2 * inv_rms * sc2, n3 = v3 * inv_rms * sc3;
        float f0 = (float)s * invf0, f1 = (float)s * invf1;
        float c0 = __cosf(f0), s0 = __sinf(f0), c1 = __cosf(f1), s1 = __sinf(f1);
        float o0 = (n0 * c0 - n2 * s0) * post;
        float o1 = (n1 * c1 - n3 * s1) * post;
        float o2 = (n0 * s0 + n2 * c0) * post;
        float o3 = (n1 * s1 + n3 * c1) * post;
        unsigned short* dst = (bx < 16)
            ? qb + ((size_t)(b * NH + bx) * S_LEN + s) * HD
            : kbuf + ((size_t)(b * NKV + (bx - 16)) * S_LEN + s) * HD;
        dst[l16] = f2bf(o0);
        dst[16 + l16] = f2bf(o1);
        dst[32 + l16] = f2bf(o2);
        dst[48 + l16] = f2bf(o3);
      }
  } else {
    int kvh = bx - 20;
    int b = row0 >> 11;
    unsigned short* vbase = vt + (size_t)(b * NKV + kvh) * HD * S_LEN;
#pragma unroll
    for (int i = 0; i < 2; ++i) {
      int s0 = (row0 & 2047) + w * 32 + i * 16 + quad * 4;
#pragma unroll
      for (int j = 0; j < 4; ++j) {
        int d = j * 16 + l16;
        s16x4 pv;
#pragma unroll
        for (int rg = 0; rg < 4; ++rg) pv[rg] = (short)f2bf(acc[i][j][rg]);
        *reinterpret_cast<s16x4*>(vbase + (size_t)d * S_LEN + s0) = pv;
      }
    }
  }
}

// ------- causal flash attention: split-S(2), GQA-shared, LDS-staged (r5 structure) -------
// + T5 setprio (null-within-noise, kept). P-transpose eliminated via permuted K-row
// loads (r3). LDS 34.8 KB/block -> 4 blocks/CU; launch_bounds(256,4).
#define CH 136                 // shorts per chunk: 256B data + 16B pad
#define TILE_SH (32 * CH)
__global__ __launch_bounds__(256, 4) void attn_kernel(const unsigned short* __restrict__ qb,
                                                      const unsigned short* __restrict__ kbuf,
                                                      const unsigned short* __restrict__ vt,
                                                      unsigned short* __restrict__ Opart,
                                                      float* __restrict__ lpart) {
  __shared__ __align__(16) unsigned short Ks[2][TILE_SH];
  __shared__ __align__(16) unsigned short Vs[2][TILE_SH];
  const size_t OZ = (size_t)BATCH * NH * S_LEN * HD;
  const size_t LZ = (size_t)BATCH * NH * S_LEN;
  int t32 = 63 - (int)(blockIdx.x >> 4);   // heavy tiles dispatched first
  int sub = blockIdx.x & 15;
  int z = sub & 1;
  int bkv = sub >> 1;
  int b = bkv >> 2, kvh = bkv & 3;
  int w = threadIdx.x >> 6;                // head within kv group
  int h = kvh * 4 + w;
  int lane = threadIdx.x & 63;
  int quad = lane >> 4, l16 = lane & 15;
  int qa = t32 * 32 + l16;                 // q-group a; group b = qa + 16
  const unsigned short* Q = qb + (size_t)(b * NH + h) * S_LEN * HD;
  const unsigned short* Kh = kbuf + (size_t)(b * NKV + kvh) * S_LEN * HD;
  const unsigned short* Vh = vt + (size_t)(b * NKV + kvh) * HD * S_LEN;

  bf16x8 bqa0 = *reinterpret_cast<const bf16x8*>(Q + (size_t)qa * HD + quad * 8);
  bf16x8 bqa1 = *reinterpret_cast<const bf16x8*>(Q + (size_t)qa * HD + 32 + quad * 8);
  bf16x8 bqb0 = *reinterpret_cast<const bf16x8*>(Q + (size_t)(qa + 16) * HD + quad * 8);
  bf16x8 bqb1 = *reinterpret_cast<const bf16x8*>(Q + (size_t)(qa + 16) * HD + 32 + quad * 8);

  bf16x8 ones;
#pragma unroll
  for (int i = 0; i < 8; ++i) ones[i] = (short)0x3F80;   // bf16 1.0

  f32x4 ot[2][4];
#pragma unroll
  for (int gq = 0; gq < 2; ++gq)
#pragma unroll
    for (int i = 0; i < 4; ++i) ot[gq][i] = (f32x4){0.f, 0.f, 0.f, 0.f};
  f32x4 ol[2] = {(f32x4){0.f, 0.f, 0.f, 0.f}, (f32x4){0.f, 0.f, 0.f, 0.f}};

  int n = (t32 >> 1) + 1;                  // key tiles for this q-tile

  auto stage = [&](int kbase, int dbuf) {
    const unsigned short* kg = Kh + (size_t)(kbase + w * 16) * HD + lane * 2;
    const unsigned short* vg = Vh + (size_t)(w * 16 + (lane >> 5)) * S_LEN + kbase + (lane & 31) * 2;
    unsigned short* kl = &Ks[dbuf][(w * 8) * CH];
    unsigned short* vl = &Vs[dbuf][(w * 8) * CH];
#pragma unroll
    for (int c = 0; c < 8; ++c) {
      gload_lds4(kg + (size_t)(2 * c) * HD, kl + c * CH);
      gload_lds4(vg + (size_t)(2 * c) * S_LEN, vl + c * CH);
    }
  };

  if (z < n) {
    stage(z << 6, 0);
    __syncthreads();

    for (int kb = z; kb < n; kb += 2) {
      int dbuf = (kb >> 1) & 1;
      bool diag = (kb == n - 1);
      if (kb + 2 < n) stage((kb + 2) << 6, dbuf ^ 1);
      int kbase = kb << 6;
      const unsigned short* Kd = Ks[dbuf];
      const unsigned short* Vd = Vs[dbuf];

      f32x4 sa[4], sb[4];
      __builtin_amdgcn_s_setprio(1);
#pragma unroll
      for (int km = 0; km < 4; ++km) {
        // permuted key row for MFMA km at A-row l16
        int kk = 32 * (km >> 1) + 4 * (km & 1) + 8 * (l16 >> 2) + (l16 & 3);
        int base = (kk >> 1) * CH + (kk & 1) * 64;
        bf16x8 k0 = *reinterpret_cast<const bf16x8*>(&Kd[base + quad * 8]);
        bf16x8 k1 = *reinterpret_cast<const bf16x8*>(&Kd[base + 32 + quad * 8]);
        f32x4 s = {0.f, 0.f, 0.f, 0.f};
        s = __builtin_amdgcn_mfma_f32_16x16x32_bf16(k0, bqa0, s, 0, 0, 0);
        s = __builtin_amdgcn_mfma_f32_16x16x32_bf16(k1, bqa1, s, 0, 0, 0);
        sa[km] = s;
        f32x4 s2 = {0.f, 0.f, 0.f, 0.f};
        s2 = __builtin_amdgcn_mfma_f32_16x16x32_bf16(k0, bqb0, s2, 0, 0, 0);
        s2 = __builtin_amdgcn_mfma_f32_16x16x32_bf16(k1, bqb1, s2, 0, 0, 0);
        sb[km] = s2;
      }
      __builtin_amdgcn_s_setprio(0);
      if (diag) {
#pragma unroll
        for (int km = 0; km < 4; ++km)
#pragma unroll
          for (int rg = 0; rg < 4; ++rg) {
            int key = kbase + 32 * (km >> 1) + 8 * quad + 4 * (km & 1) + rg;
            if (key > qa) sa[km][rg] = -1e30f;
            if (key > qa + 16) sb[km][rg] = -1e30f;
          }
      }
      unsigned int pk[4][2], qk[4][2];
#pragma unroll
      for (int km = 0; km < 4; ++km) {
        float a0 = exp2f(sa[km][0]), a1 = exp2f(sa[km][1]);
        float a2 = exp2f(sa[km][2]), a3 = exp2f(sa[km][3]);
        pk[km][0] = __builtin_amdgcn_perm(__float_as_uint(a1), __float_as_uint(a0), 0x07060302);
        pk[km][1] = __builtin_amdgcn_perm(__float_as_uint(a3), __float_as_uint(a2), 0x07060302);
        float b0 = exp2f(sb[km][0]), b1 = exp2f(sb[km][1]);
        float b2 = exp2f(sb[km][2]), b3 = exp2f(sb[km][3]);
        qk[km][0] = __builtin_amdgcn_perm(__float_as_uint(b1), __float_as_uint(b0), 0x07060302);
        qk[km][1] = __builtin_amdgcn_perm(__float_as_uint(b3), __float_as_uint(b2), 0x07060302);
      }
      i32x4 wa0 = {(int)pk[0][0], (int)pk[0][1], (int)pk[1][0], (int)pk[1][1]};
      i32x4 wa1 = {(int)pk[2][0], (int)pk[2][1], (int)pk[3][0], (int)pk[3][1]};
      i32x4 wb0 = {(int)qk[0][0], (int)qk[0][1], (int)qk[1][0], (int)qk[1][1]};
      i32x4 wb1 = {(int)qk[2][0], (int)qk[2][1], (int)qk[3][0], (int)qk[3][1]};
      bf16x8 pa0 = *reinterpret_cast<bf16x8*>(&wa0);
      bf16x8 pa1 = *reinterpret_cast<bf16x8*>(&wa1);
      bf16x8 pb0 = *reinterpret_cast<bf16x8*>(&wb0);
      bf16x8 pb1 = *reinterpret_cast<bf16x8*>(&wb1);
      __builtin_amdgcn_s_setprio(1);
      ol[0] = __builtin_amdgcn_mfma_f32_16x16x32_bf16(ones, pa0, ol[0], 0, 0, 0);
      ol[0] = __builtin_amdgcn_mfma_f32_16x16x32_bf16(ones, pa1, ol[0], 0, 0, 0);
      ol[1] = __builtin_amdgcn_mfma_f32_16x16x32_bf16(ones, pb0, ol[1], 0, 0, 0);
      ol[1] = __builtin_amdgcn_mfma_f32_16x16x32_bf16(ones, pb1, ol[1], 0, 0, 0);
#pragma unroll
      for (int dm = 0; dm < 4; ++dm) {
        int ch = dm * 8 + (l16 >> 1);
        int base = ch * CH + (l16 & 1) * 64;
        bf16x8 v0 = *reinterpret_cast<const bf16x8*>(&Vd[base + quad * 8]);
        bf16x8 v1 = *reinterpret_cast<const bf16x8*>(&Vd[base + 32 + quad * 8]);
        ot[0][dm] = __builtin_amdgcn_mfma_f32_16x16x32_bf16(v0, pa0, ot[0][dm], 0, 0, 0);
        ot[0][dm] = __builtin_amdgcn_mfma_f32_16x16x32_bf16(v1, pa1, ot[0][dm], 0, 0, 0);
        ot[1][dm] = __builtin_amdgcn_mfma_f32_16x16x32_bf16(v0, pb0, ot[1][dm], 0, 0, 0);
        ot[1][dm] = __builtin_amdgcn_mfma_f32_16x16x32_bf16(v1, pb1, ot[1][dm], 0, 0, 0);
      }
      __builtin_amdgcn_s_setprio(0);
      __syncthreads();   // drains prefetch (issued a full phase ago) + buffer swap
    }
  }

  // write unnormalized bf16 O partial + fp32 l partial for this z
  unsigned short* Oz = Opart + (size_t)z * OZ;
  float* lz = lpart + (size_t)z * LZ;
#pragma unroll
  for (int gq = 0; gq < 2; ++gq) {
    size_t base = ((size_t)(b * NH + h) * S_LEN + qa + gq * 16) * HD;
#pragma unroll
    for (int dm = 0; dm < 4; ++dm) {
      s16x4 pv;
#pragma unroll
      for (int rg = 0; rg < 4; ++rg) pv[rg] = (short)f2bf(ot[gq][dm][rg]);
      *reinterpret_cast<s16x4*>(Oz + base + dm * 16 + quad * 4) = pv;
    }
  }
  if (quad == 0) {
    size_t lb = (size_t)(b * NH + h) * S_LEN + t32 * 32 + l16;
    lz[lb] = ol[0][0];
    lz[lb + 16] = ol[1][0];
  }
}

// ------- combine split-S partials: ctx = (O0+O1)/(l0+l1), bf16 -------
__global__ __launch_bounds__(256) void attn_combine_kernel(const unsigned short* __restrict__ Opart,
                                                           const float* __restrict__ lpart,
                                                           unsigned short* __restrict__ ctx) {
  const size_t OZ = (size_t)BATCH * NH * S_LEN * HD;
  const size_t LZ = (size_t)BATCH * NH * S_LEN;
  int i8 = blockIdx.x * 256 + threadIdx.x;   // 8 elems per thread
  size_t i = (size_t)i8 * 8;
  int row = i8 >> 3;                          // (b*NH+h)*S_LEN + q
  bf16x8 a = *reinterpret_cast<const bf16x8*>(Opart + i);
  bf16x8 c = *reinterpret_cast<const bf16x8*>(Opart + OZ + i);
  float inv = 1.0f / (lpart[row] + lpart[LZ + row]);
  int q = row & 2047;
  int bh = row >> 11;
  int b = bh >> 4, h = bh & 15;
  int d0 = (i8 & 7) * 8;
  bf16x8 o;
#pragma unroll
  for (int k = 0; k < 8; ++k) {
    float fa = __uint_as_float(((unsigned int)(unsigned short)a[k]) << 16);
    float fc = __uint_as_float(((unsigned int)(unsigned short)c[k]) << 16);
    o[k] = (short)f2bf((fa + fc) * inv);
  }
  *reinterpret_cast<bf16x8*>(ctx + ((size_t)(b * S_LEN + q)) * DM + h * HD + d0) = o;
}

// ------- gemm2: out = ctx @ wot^T, 128x64 tile, direct fp32 C (r5 config) -------
__global__ __launch_bounds__(256) void gemm_bt_n64(const unsigned short* __restrict__ A,
                                                   const unsigned short* __restrict__ BT,
                                                   float* __restrict__ C,
                                                   int M, int N, int K) {
  __shared__ __align__(16) unsigned short As[128 * 64];
  __shared__ __align__(16) unsigned short Bs[64 * 64];
  int row0 = blockIdx.y * 128, col0 = blockIdx.x * 64;
  int t = threadIdx.x;
  int w = t >> 6, lane = t & 63, quad = lane >> 4, l16 = lane & 15;
  int srow = lane >> 3;
  int scol = (lane & 7) * 8;

  f32x4 acc[2][4];
#pragma unroll
  for (int i = 0; i < 2; ++i)
#pragma unroll
    for (int j = 0; j < 4; ++j) acc[i][j] = (f32x4){0.f, 0.f, 0.f, 0.f};

  for (int k0 = 0; k0 < K; k0 += 64) {
#pragma unroll
    for (int j = 0; j < 4; ++j)
      gload_lds16(A + (size_t)(row0 + w * 32 + j * 8 + srow) * K + k0 + scol,
                  &As[(w * 32 + j * 8) * 64]);
#pragma unroll
    for (int j = 0; j < 2; ++j)
      gload_lds16(BT + (size_t)(col0 + w * 16 + j * 8 + srow) * K + k0 + scol,
                  &Bs[(w * 16 + j * 8) * 64]);
    __syncthreads();
#pragma unroll
    for (int ks = 0; ks < 2; ++ks) {
      bf16x8 af[2], bfr[4];
#pragma unroll
      for (int i = 0; i < 2; ++i)
        af[i] = *reinterpret_cast<const bf16x8*>(&As[(w * 32 + i * 16 + l16) * 64 + ks * 32 + quad * 8]);
#pragma unroll
      for (int j = 0; j < 4; ++j)
        bfr[j] = *reinterpret_cast<const bf16x8*>(&Bs[(j * 16 + l16) * 64 + ks * 32 + quad * 8]);
#pragma unroll
      for (int i = 0; i < 2; ++i)
#pragma unroll
        for (int j = 0; j < 4; ++j)
          acc[i][j] = __builtin_amdgcn_mfma_f32_16x16x32_bf16(af[i], bfr[j], acc[i][j], 0, 0, 0);
    }
    __syncthreads();
  }
#pragma unroll
  for (int i = 0; i < 2; ++i)
#pragma unroll
    for (int j = 0; j < 4; ++j) {
      int row = row0 + w * 32 + i * 16 + quad * 4;
      float* Cptr = C + (size_t)row * N + col0 + j * 16 + l16;
#pragma unroll
      for (int rg = 0; rg < 4; ++rg) Cptr[(size_t)rg * N] = acc[i][j][rg];
    }
}

// ---------------- launch ----------------
extern "C" void kernel_launch(void* const* d_in, const int* in_sizes, int n_in,
                              void* d_out, int out_size, void* d_ws, size_t ws_size,
                              hipStream_t stream) {
  const float* x = (const float*)d_in[0];
  const float* Wq = (const float*)d_in[1];
  const float* Wkv = (const float*)d_in[2];
  const float* Wo = (const float*)d_in[3];
  const float* q_scale = (const float*)d_in[4];
  const float* k_scale = (const float*)d_in[5];
  float* out = (float*)d_out;

  char* ws = (char*)d_ws;
  size_t off = 0;
  auto alloc = [&](size_t bytes) {
    void* p = ws + off;
    off += (bytes + 255) & ~(size_t)255;
    return p;
  };
  unsigned short* xb = (unsigned short*)alloc((size_t)MROWS * DM * 2);
  unsigned short* wt1 = (unsigned short*)alloc((size_t)NQKV * DM * 2);   // [Wq^T ; Wkv^T]
  unsigned short* wot = (unsigned short*)alloc((size_t)DM * DM * 2);
  unsigned short* qb = (unsigned short*)alloc((size_t)BATCH * NH * S_LEN * HD * 2);
  unsigned short* kbuf = (unsigned short*)alloc((size_t)BATCH * NKV * S_LEN * HD * 2);
  unsigned short* vt = (unsigned short*)alloc((size_t)BATCH * NKV * HD * S_LEN * 2);
  unsigned short* ctx = (unsigned short*)alloc((size_t)MROWS * DM * 2);
  unsigned short* Opart = (unsigned short*)alloc(2 * (size_t)BATCH * NH * S_LEN * HD * 2);
  float* lpart = (float*)alloc(2 * (size_t)BATCH * NH * S_LEN * 4);

  prep_kernel<<<4736, 256, 0, stream>>>(x, xb, Wq, Wkv, Wo, wt1, wot);

  gemm1_fused<<<dim3(NQKV / 64, MROWS / 128), 256, 0, stream>>>(xb, wt1, q_scale, k_scale,
                                                                qb, kbuf, vt, DM);

  attn_kernel<<<1024, 256, 0, stream>>>(qb, kbuf, vt, Opart, lpart);
  attn_combine_kernel<<<(BATCH * NH * S_LEN * HD / 8) / 256, 256, 0, stream>>>(Opart, lpart, ctx);

  gemm_bt_n64<<<dim3(DM / 64, MROWS / 128), 256, 0, stream>>>(ctx, wot, out, MROWS, DM, DM);
}